// Round 2
// baseline (17967.390 us; speedup 1.0000x reference)
//
#include <hip/hip_runtime.h>
#include <hip/hip_bf16.h>

// LocalAttention (T5-style blocked local attention).
// T=4096, B=4, C=1024, H=16, D=64, L=128, NB=32, window = 3 blocks = 384 keys.
//
// Round 1: workspace cut 272MB -> 160MB (suspected ws_size cap caused round-0
// early return). q/k/v stored bf16 [B][H][T][D]; bias computed inline from a
// 32-entry LDS table (integer-threshold bucket == reference fp32 log formula,
// boundary-exactness verified). ao fp32; all accumulation fp32.

#define T_LEN 4096
#define BATCH 4
#define CDIM 1024
#define NHEAD 16
#define HDIM 64
#define BLK 128
#define NBLK 32
#define KW 384
#define QK_SCALE 0.125f  // HDIM^-0.5

__device__ __forceinline__ float bf2f(unsigned int u16) {
    union { unsigned int i; float f; } v; v.i = u16 << 16; return v.f;
}
__device__ __forceinline__ float bf_lo(unsigned int w) {
    union { unsigned int i; float f; } v; v.i = w << 16; return v.f;
}
__device__ __forceinline__ float bf_hi(unsigned int w) {
    union { unsigned int i; float f; } v; v.i = w & 0xffff0000u; return v.f;
}
__device__ __forceinline__ unsigned short f2b(float f) {
    __hip_bfloat16 h = __float2bfloat16(f);
    return *reinterpret_cast<unsigned short*>(&h);
}

// ---------------- projection GEMM (q,k,v fused via blockIdx.z) ----------------
// M = B*T = 16384 (m = b*T + t), N = 1024, K = 1024. Output bf16 [B][H][T][D].
__global__ __launch_bounds__(256) void proj_qkv(
    const float* __restrict__ hidden,
    const float* __restrict__ Wq, const float* __restrict__ Wk,
    const float* __restrict__ Wv,
    unsigned short* __restrict__ qb, unsigned short* __restrict__ kb,
    unsigned short* __restrict__ vb)
{
    const int z = blockIdx.z;
    const float* W = (z == 0) ? Wq : (z == 1 ? Wk : Wv);
    unsigned short* outb = (z == 0) ? qb : (z == 1 ? kb : vb);
    const float scale = (z == 0) ? QK_SCALE : 1.0f;

    __shared__ float As[16][64];
    __shared__ float Bs[16][64];

    const int tid = threadIdx.x;
    const int tx = tid & 15, ty = tid >> 4;
    const int mBase = blockIdx.x * 64;
    const int nBase = blockIdx.y * 64;

    float acc[4][4] = {};

    const int aRow = tid >> 2;
    const int aCol = (tid & 3) * 4;
    const int m = mBase + aRow;
    const int b = m >> 12;       // m / 4096
    const int t = m & 4095;
    const float* xRow = hidden + ((size_t)t * BATCH + b) * CDIM;

    const int bRow = tid >> 4;
    const int bCol = (tid & 15) * 4;

    for (int k0 = 0; k0 < CDIM; k0 += 16) {
        float4 av = *(const float4*)(xRow + k0 + aCol);
        float4 bv = *(const float4*)(W + (size_t)(k0 + bRow) * CDIM + nBase + bCol);
        __syncthreads();
        As[aCol + 0][aRow] = av.x;
        As[aCol + 1][aRow] = av.y;
        As[aCol + 2][aRow] = av.z;
        As[aCol + 3][aRow] = av.w;
        *(float4*)&Bs[bRow][bCol] = bv;
        __syncthreads();
#pragma unroll
        for (int kk = 0; kk < 16; ++kk) {
            float4 a4 = *(const float4*)&As[kk][ty * 4];
            float4 b4 = *(const float4*)&Bs[kk][tx * 4];
            float ar[4] = {a4.x, a4.y, a4.z, a4.w};
            float br[4] = {b4.x, b4.y, b4.z, b4.w};
#pragma unroll
            for (int i = 0; i < 4; ++i)
#pragma unroll
                for (int j = 0; j < 4; ++j) acc[i][j] += ar[i] * br[j];
        }
    }

    const int h = nBase >> 6;          // nBase is a multiple of 64
    const int dBase = tx * 4;
#pragma unroll
    for (int i = 0; i < 4; ++i) {
        int mm = mBase + ty * 4 + i;
        int bb = mm >> 12, tt = mm & 4095;
        ushort4 o;
        o.x = f2b(acc[i][0] * scale);
        o.y = f2b(acc[i][1] * scale);
        o.z = f2b(acc[i][2] * scale);
        o.w = f2b(acc[i][3] * scale);
        *(ushort4*)&outb[(((size_t)bb * NHEAD + h) * T_LEN + tt) * HDIM + dBase] = o;
    }
}

// ---------------- relative position bucket (== reference fp32 log formula) ----
__device__ __forceinline__ int rel_bucket(int rel) {
    int rb = (rel > 0) ? 16 : 0;
    int rp = abs(rel);
    int bu;
    if (rp < 8) bu = rp;
    else if (rp < 12) bu = 8;
    else if (rp < 16) bu = 9;
    else if (rp < 23) bu = 10;
    else if (rp < 32) bu = 11;
    else if (rp < 46) bu = 12;
    else if (rp < 64) bu = 13;
    else if (rp < 91) bu = 14;
    else bu = 15;   // includes the >=128 clip
    return rb + bu;
}

// ---------------- attention ----------------
// grid (NBLK, NHEAD, BATCH), 128 threads; thread r owns q-row r.
__global__ __launch_bounds__(128) void attn_kernel(
    const unsigned short* __restrict__ qb, const unsigned short* __restrict__ kb,
    const unsigned short* __restrict__ vb, const float* __restrict__ table,
    float* __restrict__ ao)
{
    const int n = blockIdx.x;
    const int h = blockIdx.y;
    const int b = blockIdx.z;
    const int r = threadIdx.x;

    __shared__ float kS[32][64];
    __shared__ float vS[32][64];
    __shared__ float tbl[32];

    if (r < 32) tbl[r] = table[r * NHEAD + h];

    // q row -> registers (fp32)
    const unsigned short* qRow =
        qb + (((size_t)b * NHEAD + h) * T_LEN + n * BLK + r) * HDIM;
    float qr[64];
    const uint4* q4 = (const uint4*)qRow;   // 16B = 8 bf16 each
#pragma unroll
    for (int i = 0; i < 8; ++i) {
        uint4 w = q4[i];
        qr[i * 8 + 0] = bf_lo(w.x); qr[i * 8 + 1] = bf_hi(w.x);
        qr[i * 8 + 2] = bf_lo(w.y); qr[i * 8 + 3] = bf_hi(w.y);
        qr[i * 8 + 4] = bf_lo(w.z); qr[i * 8 + 5] = bf_hi(w.z);
        qr[i * 8 + 6] = bf_lo(w.w); qr[i * 8 + 7] = bf_hi(w.w);
    }

    const unsigned short* kBase = kb + ((size_t)b * NHEAD + h) * T_LEN * HDIM;
    const unsigned short* vBase = vb + ((size_t)b * NHEAD + h) * T_LEN * HDIM;

    float mrun = -1e30f, l = 0.f;
    float acc[64] = {};

    for (int c = 0; c < 12; ++c) {
        const int tk0 = (n - 1) * BLK + c * 32;  // token of first key in chunk
        __syncthreads();
        // 32 rows x 64 bf16 per buffer = 256 uint4 slots; 2 slots/thread/buffer
#pragma unroll
        for (int u = 0; u < 2; ++u) {
            int s = r + u * 128;
            int row = s >> 3;
            int colB = (s & 7) * 8;
            int tok = tk0 + row;
            uint4 kw = make_uint4(0, 0, 0, 0), vw = make_uint4(0, 0, 0, 0);
            if (tok >= 0 && tok < T_LEN) {
                kw = *(const uint4*)(kBase + (size_t)tok * HDIM + colB);
                vw = *(const uint4*)(vBase + (size_t)tok * HDIM + colB);
            }
            float* kd = &kS[row][colB];
            kd[0] = bf_lo(kw.x); kd[1] = bf_hi(kw.x);
            kd[2] = bf_lo(kw.y); kd[3] = bf_hi(kw.y);
            kd[4] = bf_lo(kw.z); kd[5] = bf_hi(kw.z);
            kd[6] = bf_lo(kw.w); kd[7] = bf_hi(kw.w);
            float* vd = &vS[row][colB];
            vd[0] = bf_lo(vw.x); vd[1] = bf_hi(vw.x);
            vd[2] = bf_lo(vw.y); vd[3] = bf_hi(vw.y);
            vd[4] = bf_lo(vw.z); vd[5] = bf_hi(vw.z);
            vd[6] = bf_lo(vw.w); vd[7] = bf_hi(vw.w);
        }
        __syncthreads();

        float s[32];
        float cmax = -1e30f;
#pragma unroll
        for (int j = 0; j < 32; ++j) {
            float dot = 0.f;
#pragma unroll
            for (int d = 0; d < 64; ++d) dot += qr[d] * kS[j][d];
            dot += tbl[rel_bucket(c * 32 + j - r - BLK)];
            s[j] = dot;
            cmax = fmaxf(cmax, dot);
        }
        float mnew = fmaxf(mrun, cmax);
        float sc = __expf(mrun - mnew);
        l *= sc;
#pragma unroll
        for (int d = 0; d < 64; ++d) acc[d] *= sc;
#pragma unroll
        for (int j = 0; j < 32; ++j) {
            float p = __expf(s[j] - mnew);
            l += p;
#pragma unroll
            for (int d = 0; d < 64; ++d) acc[d] += p * vS[j][d];
        }
        mrun = mnew;
    }

    const float inv = 1.f / l;
    float* outRow = ao + ((size_t)b * T_LEN + n * BLK + r) * CDIM + h * HDIM;
#pragma unroll
    for (int d = 0; d < 64; d += 4) {
        float4 o = make_float4(acc[d] * inv, acc[d + 1] * inv,
                               acc[d + 2] * inv, acc[d + 3] * inv);
        *(float4*)(outRow + d) = o;
    }
}

// ---------------- output projection (writes transposed (T,B,C)) ----------------
__global__ __launch_bounds__(256) void out_proj(
    const float* __restrict__ ao, const float* __restrict__ Wo,
    float* __restrict__ out)
{
    __shared__ float As[16][64];
    __shared__ float Bs[16][64];

    const int tid = threadIdx.x;
    const int tx = tid & 15, ty = tid >> 4;
    const int mBase = blockIdx.x * 64;
    const int nBase = blockIdx.y * 64;

    float acc[4][4] = {};

    const int aRow = tid >> 2;
    const int aCol = (tid & 3) * 4;
    const float* xRow = ao + (size_t)(mBase + aRow) * CDIM;

    const int bRow = tid >> 4;
    const int bCol = (tid & 15) * 4;

    for (int k0 = 0; k0 < CDIM; k0 += 16) {
        float4 av = *(const float4*)(xRow + k0 + aCol);
        float4 bv = *(const float4*)(Wo + (size_t)(k0 + bRow) * CDIM + nBase + bCol);
        __syncthreads();
        As[aCol + 0][aRow] = av.x;
        As[aCol + 1][aRow] = av.y;
        As[aCol + 2][aRow] = av.z;
        As[aCol + 3][aRow] = av.w;
        *(float4*)&Bs[bRow][bCol] = bv;
        __syncthreads();
#pragma unroll
        for (int kk = 0; kk < 16; ++kk) {
            float4 a4 = *(const float4*)&As[kk][ty * 4];
            float4 b4 = *(const float4*)&Bs[kk][tx * 4];
            float ar[4] = {a4.x, a4.y, a4.z, a4.w};
            float br[4] = {b4.x, b4.y, b4.z, b4.w};
#pragma unroll
            for (int i = 0; i < 4; ++i)
#pragma unroll
                for (int j = 0; j < 4; ++j) acc[i][j] += ar[i] * br[j];
        }
    }

#pragma unroll
    for (int i = 0; i < 4; ++i) {
        int mm = mBase + ty * 4 + i;
        int bb = mm >> 12, tt = mm & 4095;
        float4 o = make_float4(acc[i][0], acc[i][1], acc[i][2], acc[i][3]);
        *(float4*)&out[((size_t)tt * BATCH + bb) * CDIM + nBase + tx * 4] = o;
    }
}

extern "C" void kernel_launch(void* const* d_in, const int* in_sizes, int n_in,
                              void* d_out, int out_size, void* d_ws, size_t ws_size,
                              hipStream_t stream) {
    const float* hidden = (const float*)d_in[0];
    const float* Wq = (const float*)d_in[1];
    const float* Wk = (const float*)d_in[2];
    const float* Wv = (const float*)d_in[3];
    const float* Wo = (const float*)d_in[4];
    const float* table = (const float*)d_in[5];
    float* out = (float*)d_out;

    const size_t qkvElems = (size_t)BATCH * NHEAD * T_LEN * HDIM;   // 16.78M
    const size_t aoElems = (size_t)BATCH * T_LEN * CDIM;            // 16.78M
    // bf16 q,k,v (2B) + fp32 ao (4B) = 160 MB total
    const size_t needed = 3 * qkvElems * 2 + aoElems * 4;
    if (ws_size < needed) return;

    unsigned short* qb = (unsigned short*)d_ws;
    unsigned short* kb = qb + qkvElems;
    unsigned short* vb = kb + qkvElems;
    float* ao = (float*)(vb + qkvElems);   // byte offset 100,663,296 (16B aligned)

    proj_qkv<<<dim3(256, 16, 3), 256, 0, stream>>>(hidden, Wq, Wk, Wv, qb, kb, vb);
    attn_kernel<<<dim3(NBLK, NHEAD, BATCH), 128, 0, stream>>>(qb, kb, vb, table, ao);
    out_proj<<<dim3(256, 16), 256, 0, stream>>>(ao, Wo, out);
}

// Round 3
// 1866.551 us; speedup vs baseline: 9.6260x; 9.6260x over previous
//
#include <hip/hip_runtime.h>
#include <hip/hip_bf16.h>

// LocalAttention (T5-style blocked local attention).
// T=4096, B=4, C=1024, H=16, D=64, L=128, NB=32, window = 3 blocks = 384 keys.
//
// Round 2: attention rewritten with MFMA 16x16x32 bf16 (round-1 scalar version
// spilled ~21GB to scratch: VGPR 256, VALUBusy 2%). Flash-style: 4 waves/block,
// wave owns 32 q-rows; 6 key-tiles of 64; online softmax in C-layout with
// 16-lane-group shfl reductions; P via per-wave LDS round-trip; V transposed
// in LDS; all LDS 2D arrays padded to stride 72 (16B-aligned, conflict-light).

#define T_LEN 4096
#define BATCH 4
#define CDIM 1024
#define NHEAD 16
#define HDIM 64
#define BLK 128
#define NBLK 32
#define KW 384
#define QK_SCALE 0.125f  // HDIM^-0.5

typedef __attribute__((ext_vector_type(8))) short bf16x8;
typedef __attribute__((ext_vector_type(4))) float f32x4;

__device__ __forceinline__ float bf_lo(unsigned int w) {
    union { unsigned int i; float f; } v; v.i = w << 16; return v.f;
}
__device__ __forceinline__ float bf_hi(unsigned int w) {
    union { unsigned int i; float f; } v; v.i = w & 0xffff0000u; return v.f;
}
__device__ __forceinline__ unsigned short f2b(float f) {
    __hip_bfloat16 h = __float2bfloat16(f);
    return *reinterpret_cast<unsigned short*>(&h);
}

// ---------------- projection GEMM (q,k,v fused via blockIdx.z) ----------------
__global__ __launch_bounds__(256) void proj_qkv(
    const float* __restrict__ hidden,
    const float* __restrict__ Wq, const float* __restrict__ Wk,
    const float* __restrict__ Wv,
    unsigned short* __restrict__ qb, unsigned short* __restrict__ kb,
    unsigned short* __restrict__ vb)
{
    const int z = blockIdx.z;
    const float* W = (z == 0) ? Wq : (z == 1 ? Wk : Wv);
    unsigned short* outb = (z == 0) ? qb : (z == 1 ? kb : vb);
    const float scale = (z == 0) ? QK_SCALE : 1.0f;

    __shared__ float As[16][64];
    __shared__ float Bs[16][64];

    const int tid = threadIdx.x;
    const int tx = tid & 15, ty = tid >> 4;
    const int mBase = blockIdx.x * 64;
    const int nBase = blockIdx.y * 64;

    float acc[4][4] = {};

    const int aRow = tid >> 2;
    const int aCol = (tid & 3) * 4;
    const int m = mBase + aRow;
    const int b = m >> 12;
    const int t = m & 4095;
    const float* xRow = hidden + ((size_t)t * BATCH + b) * CDIM;

    const int bRow = tid >> 4;
    const int bCol = (tid & 15) * 4;

    for (int k0 = 0; k0 < CDIM; k0 += 16) {
        float4 av = *(const float4*)(xRow + k0 + aCol);
        float4 bv = *(const float4*)(W + (size_t)(k0 + bRow) * CDIM + nBase + bCol);
        __syncthreads();
        As[aCol + 0][aRow] = av.x;
        As[aCol + 1][aRow] = av.y;
        As[aCol + 2][aRow] = av.z;
        As[aCol + 3][aRow] = av.w;
        *(float4*)&Bs[bRow][bCol] = bv;
        __syncthreads();
#pragma unroll
        for (int kk = 0; kk < 16; ++kk) {
            float4 a4 = *(const float4*)&As[kk][ty * 4];
            float4 b4 = *(const float4*)&Bs[kk][tx * 4];
            float ar[4] = {a4.x, a4.y, a4.z, a4.w};
            float br[4] = {b4.x, b4.y, b4.z, b4.w};
#pragma unroll
            for (int i = 0; i < 4; ++i)
#pragma unroll
                for (int j = 0; j < 4; ++j) acc[i][j] += ar[i] * br[j];
        }
    }

    const int h = nBase >> 6;
    const int dBase = tx * 4;
#pragma unroll
    for (int i = 0; i < 4; ++i) {
        int mm = mBase + ty * 4 + i;
        int bb = mm >> 12, tt = mm & 4095;
        ushort4 o;
        o.x = f2b(acc[i][0] * scale);
        o.y = f2b(acc[i][1] * scale);
        o.z = f2b(acc[i][2] * scale);
        o.w = f2b(acc[i][3] * scale);
        *(ushort4*)&outb[(((size_t)bb * NHEAD + h) * T_LEN + tt) * HDIM + dBase] = o;
    }
}

// ---------------- relative position bucket (== reference fp32 log formula) ----
__device__ __forceinline__ int rel_bucket(int rel) {
    int rb = (rel > 0) ? 16 : 0;
    int rp = abs(rel);
    int bu;
    if (rp < 8) bu = rp;
    else if (rp < 12) bu = 8;
    else if (rp < 16) bu = 9;
    else if (rp < 23) bu = 10;
    else if (rp < 32) bu = 11;
    else if (rp < 46) bu = 12;
    else if (rp < 64) bu = 13;
    else if (rp < 91) bu = 14;
    else bu = 15;
    return rb + bu;
}

// ---------------- MFMA attention ----------------
// grid (NBLK, NHEAD, BATCH), 256 threads = 4 waves; wave w owns q-rows
// [32w, 32w+32). 6 key-tiles of 64 keys, online softmax.
#define QS_STR 72
#define KS_STR 72
#define VT_STR 72
#define PL_STR 72

__global__ __launch_bounds__(256) void attn_mfma(
    const unsigned short* __restrict__ qb, const unsigned short* __restrict__ kb,
    const unsigned short* __restrict__ vb, const float* __restrict__ table,
    float* __restrict__ ao)
{
    const int n = blockIdx.x;
    const int h = blockIdx.y;
    const int b = blockIdx.z;
    const int tid = threadIdx.x;
    const int w = tid >> 6;
    const int lane = tid & 63;
    const int g = lane >> 4;      // 4-lane-group row block
    const int li = lane & 15;

    __shared__ short Qs[128 * QS_STR];       // [q][d]
    __shared__ short Ks[64 * KS_STR];        // [key][d]
    __shared__ short Vt[64 * VT_STR];        // [d][key]
    __shared__ short Pl[4][32 * PL_STR];     // per-wave [q][key]
    __shared__ float ldsb[512];              // bias LUT by (kk - r + 127)

    const unsigned short* qBase = qb + (((size_t)b * NHEAD + h) * T_LEN + (size_t)n * BLK) * HDIM;
    const unsigned short* kBase = kb + ((size_t)b * NHEAD + h) * T_LEN * HDIM;
    const unsigned short* vBase = vb + ((size_t)b * NHEAD + h) * T_LEN * HDIM;

    // bias LUT: idx = kk - r + 127 in [0,510]; rel = idx - 255
    for (int i = tid; i < 512; i += 256) {
        ldsb[i] = table[rel_bucket(i - 255) * NHEAD + h];
    }
    // stage Q: 128 rows x 8 chunks of 8 bf16
#pragma unroll
    for (int u = 0; u < 4; ++u) {
        int c = tid + u * 256;
        int row = c >> 3, ch = c & 7;
        *(bf16x8*)&Qs[row * QS_STR + ch * 8] =
            *(const bf16x8*)(qBase + (size_t)row * HDIM + ch * 8);
    }
    __syncthreads();

    // Q A-frags (row = li, k = d = ks*32 + g*8 + j)
    bf16x8 aq[2][2];
#pragma unroll
    for (int mi = 0; mi < 2; ++mi)
#pragma unroll
        for (int ks = 0; ks < 2; ++ks)
            aq[mi][ks] = *(bf16x8*)&Qs[(w * 32 + mi * 16 + li) * QS_STR + ks * 32 + g * 8];

    f32x4 oacc[2][4];
    float m_run[2][4], l_run[2][4], scl[2][4];
#pragma unroll
    for (int mi = 0; mi < 2; ++mi)
#pragma unroll
        for (int r4 = 0; r4 < 4; ++r4) {
            oacc[mi][r4] = (f32x4){0.f, 0.f, 0.f, 0.f};
            m_run[mi][r4] = -1e30f;
            l_run[mi][r4] = 0.f;
        }

    for (int kt = 0; kt < 6; ++kt) {
        // ---- stage 64 keys of K (row-major) and V (transposed) ----
        __syncthreads();
        const int tk0 = (n - 1) * BLK + kt * 64;
#pragma unroll
        for (int u = 0; u < 2; ++u) {
            int c = tid + u * 256;          // 0..511
            int row = c >> 3, ch = c & 7;
            int tok = tk0 + row;
            bf16x8 kv = {0, 0, 0, 0, 0, 0, 0, 0};
            bf16x8 vv = {0, 0, 0, 0, 0, 0, 0, 0};
            if (tok >= 0 && tok < T_LEN) {
                kv = *(const bf16x8*)(kBase + (size_t)tok * HDIM + ch * 8);
                vv = *(const bf16x8*)(vBase + (size_t)tok * HDIM + ch * 8);
            }
            *(bf16x8*)&Ks[row * KS_STR + ch * 8] = kv;
#pragma unroll
            for (int j = 0; j < 8; ++j)
                Vt[(ch * 8 + j) * VT_STR + row] = vv[j];
        }
        __syncthreads();

        // ---- S = Q K^T (per wave: 32q x 64k) ----
        f32x4 sacc[2][4];
#pragma unroll
        for (int mi = 0; mi < 2; ++mi)
#pragma unroll
            for (int ni = 0; ni < 4; ++ni)
                sacc[mi][ni] = (f32x4){0.f, 0.f, 0.f, 0.f};
#pragma unroll
        for (int ks = 0; ks < 2; ++ks) {
            bf16x8 bk[4];
#pragma unroll
            for (int ni = 0; ni < 4; ++ni)
                bk[ni] = *(bf16x8*)&Ks[(ni * 16 + li) * KS_STR + ks * 32 + g * 8];
#pragma unroll
            for (int mi = 0; mi < 2; ++mi)
#pragma unroll
                for (int ni = 0; ni < 4; ++ni)
                    sacc[mi][ni] = __builtin_amdgcn_mfma_f32_16x16x32_bf16(
                        aq[mi][ks], bk[ni], sacc[mi][ni], 0, 0, 0);
        }

        // ---- bias + online softmax (C-layout: row = g*4+reg, col = li) ----
#pragma unroll
        for (int mi = 0; mi < 2; ++mi) {
            const int rq = w * 32 + mi * 16 + g * 4;
#pragma unroll
            for (int reg = 0; reg < 4; ++reg) {
                const int r = rq + reg;
                float sv[4];
#pragma unroll
                for (int ni = 0; ni < 4; ++ni) {
                    int kk = kt * 64 + ni * 16 + li;
                    sv[ni] = sacc[mi][ni][reg] + ldsb[kk - r + 127];
                }
                float tm = fmaxf(fmaxf(sv[0], sv[1]), fmaxf(sv[2], sv[3]));
                tm = fmaxf(tm, __shfl_xor(tm, 1));
                tm = fmaxf(tm, __shfl_xor(tm, 2));
                tm = fmaxf(tm, __shfl_xor(tm, 4));
                tm = fmaxf(tm, __shfl_xor(tm, 8));
                float mold = m_run[mi][reg];
                float mnew = fmaxf(mold, tm);
                float sc = __expf(mold - mnew);
                float ps = 0.f;
                unsigned short pb[4];
#pragma unroll
                for (int ni = 0; ni < 4; ++ni) {
                    float pv = __expf(sv[ni] - mnew);
                    ps += pv;
                    pb[ni] = f2b(pv);
                }
                ps += __shfl_xor(ps, 1);
                ps += __shfl_xor(ps, 2);
                ps += __shfl_xor(ps, 4);
                ps += __shfl_xor(ps, 8);
                l_run[mi][reg] = l_run[mi][reg] * sc + ps;
                m_run[mi][reg] = mnew;
                scl[mi][reg] = sc;
                // write P tile (bf16) to per-wave LDS
#pragma unroll
                for (int ni = 0; ni < 4; ++ni)
                    Pl[w][(mi * 16 + g * 4 + reg) * PL_STR + ni * 16 + li] = (short)pb[ni];
            }
        }
        // rescale O
#pragma unroll
        for (int mi = 0; mi < 2; ++mi)
#pragma unroll
            for (int dn = 0; dn < 4; ++dn)
#pragma unroll
                for (int reg = 0; reg < 4; ++reg)
                    oacc[mi][dn][reg] *= scl[mi][reg];

        __syncthreads();  // P writes visible (also keeps waves in phase)

        // ---- O += P V (A = P: row=li q-local, k=key; B = Vt: col=li d-local) ----
#pragma unroll
        for (int ks = 0; ks < 2; ++ks) {
            bf16x8 ap[2], bv[4];
#pragma unroll
            for (int mi = 0; mi < 2; ++mi)
                ap[mi] = *(bf16x8*)&Pl[w][(mi * 16 + li) * PL_STR + ks * 32 + g * 8];
#pragma unroll
            for (int dn = 0; dn < 4; ++dn)
                bv[dn] = *(bf16x8*)&Vt[(dn * 16 + li) * VT_STR + ks * 32 + g * 8];
#pragma unroll
            for (int mi = 0; mi < 2; ++mi)
#pragma unroll
                for (int dn = 0; dn < 4; ++dn)
                    oacc[mi][dn] = __builtin_amdgcn_mfma_f32_16x16x32_bf16(
                        ap[mi], bv[dn], oacc[mi][dn], 0, 0, 0);
        }
    }

    // ---- normalize + write out (ao fp32 [b][t][c]) ----
#pragma unroll
    for (int mi = 0; mi < 2; ++mi) {
#pragma unroll
        for (int reg = 0; reg < 4; ++reg) {
            float inv = 1.f / l_run[mi][reg];
            int t = n * BLK + w * 32 + mi * 16 + g * 4 + reg;
            float* orow = ao + ((size_t)b * T_LEN + t) * CDIM + h * HDIM;
#pragma unroll
            for (int dn = 0; dn < 4; ++dn)
                orow[dn * 16 + li] = oacc[mi][dn][reg] * inv;
        }
    }
}

// ---------------- output projection (writes transposed (T,B,C)) ----------------
__global__ __launch_bounds__(256) void out_proj(
    const float* __restrict__ ao, const float* __restrict__ Wo,
    float* __restrict__ out)
{
    __shared__ float As[16][64];
    __shared__ float Bs[16][64];

    const int tid = threadIdx.x;
    const int tx = tid & 15, ty = tid >> 4;
    const int mBase = blockIdx.x * 64;
    const int nBase = blockIdx.y * 64;

    float acc[4][4] = {};

    const int aRow = tid >> 2;
    const int aCol = (tid & 3) * 4;
    const float* xRow = ao + (size_t)(mBase + aRow) * CDIM;

    const int bRow = tid >> 4;
    const int bCol = (tid & 15) * 4;

    for (int k0 = 0; k0 < CDIM; k0 += 16) {
        float4 av = *(const float4*)(xRow + k0 + aCol);
        float4 bv = *(const float4*)(Wo + (size_t)(k0 + bRow) * CDIM + nBase + bCol);
        __syncthreads();
        As[aCol + 0][aRow] = av.x;
        As[aCol + 1][aRow] = av.y;
        As[aCol + 2][aRow] = av.z;
        As[aCol + 3][aRow] = av.w;
        *(float4*)&Bs[bRow][bCol] = bv;
        __syncthreads();
#pragma unroll
        for (int kk = 0; kk < 16; ++kk) {
            float4 a4 = *(const float4*)&As[kk][ty * 4];
            float4 b4 = *(const float4*)&Bs[kk][tx * 4];
            float ar[4] = {a4.x, a4.y, a4.z, a4.w};
            float br[4] = {b4.x, b4.y, b4.z, b4.w};
#pragma unroll
            for (int i = 0; i < 4; ++i)
#pragma unroll
                for (int j = 0; j < 4; ++j) acc[i][j] += ar[i] * br[j];
        }
    }

#pragma unroll
    for (int i = 0; i < 4; ++i) {
        int mm = mBase + ty * 4 + i;
        int bb = mm >> 12, tt = mm & 4095;
        float4 o = make_float4(acc[i][0], acc[i][1], acc[i][2], acc[i][3]);
        *(float4*)&out[((size_t)tt * BATCH + bb) * CDIM + nBase + tx * 4] = o;
    }
}

extern "C" void kernel_launch(void* const* d_in, const int* in_sizes, int n_in,
                              void* d_out, int out_size, void* d_ws, size_t ws_size,
                              hipStream_t stream) {
    const float* hidden = (const float*)d_in[0];
    const float* Wq = (const float*)d_in[1];
    const float* Wk = (const float*)d_in[2];
    const float* Wv = (const float*)d_in[3];
    const float* Wo = (const float*)d_in[4];
    const float* table = (const float*)d_in[5];
    float* out = (float*)d_out;

    const size_t qkvElems = (size_t)BATCH * NHEAD * T_LEN * HDIM;   // 16.78M
    const size_t aoElems = (size_t)BATCH * T_LEN * CDIM;            // 16.78M
    const size_t needed = 3 * qkvElems * 2 + aoElems * 4;           // 160 MB
    if (ws_size < needed) return;

    unsigned short* qb = (unsigned short*)d_ws;
    unsigned short* kb = qb + qkvElems;
    unsigned short* vb = kb + qkvElems;
    float* ao = (float*)(vb + qkvElems);

    proj_qkv<<<dim3(256, 16, 3), 256, 0, stream>>>(hidden, Wq, Wk, Wv, qb, kb, vb);
    attn_mfma<<<dim3(NBLK, NHEAD, BATCH), 256, 0, stream>>>(qb, kb, vb, table, ao);
    out_proj<<<dim3(256, 16), 256, 0, stream>>>(ao, Wo, out);
}

// Round 4
// 387.966 us; speedup vs baseline: 46.3118x; 4.8111x over previous
//
#include <hip/hip_runtime.h>
#include <hip/hip_bf16.h>

// LocalAttention (T5-style blocked local attention).
// T=4096, B=4, C=1024, H=16, D=64, L=128, NB=32, window = 3 blocks = 384 keys.
//
// Round 3: all GEMMs moved to MFMA bf16 (round-2 fp32 proj was VALU-bound at
// 71% of 157TF). Weights split hi+lo bf16 (compensated, ~fp32 quality) and
// pre-transposed to [n][k]; x converted to bf16 [m][k]; m97-style 128x128
// tile, BK=64, global_load_lds width 16. ao stored bf16, aliased onto xb.

#define T_LEN 4096
#define BATCH 4
#define CDIM 1024
#define NHEAD 16
#define HDIM 64
#define BLK 128
#define NBLK 32

typedef __attribute__((ext_vector_type(8))) short bf16x8;
typedef __attribute__((ext_vector_type(4))) float f32x4;

__device__ __forceinline__ unsigned short f2b(float f) {
    __hip_bfloat16 h = __float2bfloat16(f);
    return *reinterpret_cast<unsigned short*>(&h);
}
__device__ __forceinline__ float b2f(unsigned short u) {
    union { unsigned int i; float f; } v; v.i = (unsigned int)u << 16; return v.f;
}
__device__ __forceinline__ void gl_lds16(const void* g, void* l) {
    __builtin_amdgcn_global_load_lds(
        (const __attribute__((address_space(1))) unsigned int*)g,
        (__attribute__((address_space(3))) unsigned int*)l, 16, 0, 0);
}

// ---- convert x: hidden (T,B,C) fp32 -> xb bf16 [m=b*T+t][k=c] ----
__global__ __launch_bounds__(256) void conv_x(const float* __restrict__ hidden,
                                              unsigned short* __restrict__ xb) {
    int chunk = blockIdx.x * 256 + threadIdx.x;   // 2,097,152 chunks of 8 elems
    int c8 = chunk & 127;
    int rem = chunk >> 7;                          // = t*4 + b
    int b = rem & 3;
    int t = rem >> 2;
    const float* src = hidden + ((size_t)rem << 10) + c8 * 8;
    float4 v0 = *(const float4*)src;
    float4 v1 = *(const float4*)(src + 4);
    bf16x8 o;
    o[0] = (short)f2b(v0.x); o[1] = (short)f2b(v0.y);
    o[2] = (short)f2b(v0.z); o[3] = (short)f2b(v0.w);
    o[4] = (short)f2b(v1.x); o[5] = (short)f2b(v1.y);
    o[6] = (short)f2b(v1.z); o[7] = (short)f2b(v1.w);
    *(bf16x8*)&xb[((size_t)(b * T_LEN + t) << 10) + c8 * 8] = o;
}

// ---- convert + transpose weights -> wt: [WqHi,WkHi,WvHi,WoT,WqLo,WkLo,WvLo]
// each [n][k] bf16, 1M elems. Wq pre-scaled by 0.125 (exact pow2).
__global__ __launch_bounds__(256) void conv_w(
    const float* __restrict__ W0, const float* __restrict__ W1,
    const float* __restrict__ W2, const float* __restrict__ W3,
    unsigned short* __restrict__ wt)
{
    const int z = blockIdx.z;
    const float* W = (z == 0) ? W0 : (z == 1) ? W1 : (z == 2) ? W2 : W3;
    const float scale = (z == 0) ? 0.125f : 1.0f;
    unsigned short* hi = wt + (size_t)z * (CDIM * CDIM);
    unsigned short* lo = (z < 3) ? wt + (size_t)(4 + z) * (CDIM * CDIM) : nullptr;
    __shared__ float tile[32][33];
    const int r = threadIdx.x >> 5;   // 0..7
    const int c = threadIdx.x & 31;
    const int k0 = blockIdx.x * 32;
    const int n0 = blockIdx.y * 32;
#pragma unroll
    for (int i = 0; i < 4; ++i)
        tile[r + i * 8][c] = W[(size_t)(k0 + r + i * 8) * CDIM + n0 + c] * scale;
    __syncthreads();
#pragma unroll
    for (int i = 0; i < 4; ++i) {
        int nn = r + i * 8;
        float f = tile[c][nn];                    // = W[k0+c][n0+nn] * scale
        unsigned short h = f2b(f);
        hi[(size_t)(n0 + nn) * CDIM + k0 + c] = h;
        if (lo) lo[(size_t)(n0 + nn) * CDIM + k0 + c] = f2b(f - b2f(h));
    }
}

// ---- projection GEMM: out = xb @ (Whi + Wlo), MFMA bf16, 128x128 tile ----
// grid (128, 8, 3), 256 threads = 4 waves (2x2), BK=64, 16 K-steps.
__global__ __launch_bounds__(256) void proj_mfma(
    const unsigned short* __restrict__ xb,
    const unsigned short* __restrict__ wt,
    unsigned short* __restrict__ qb, unsigned short* __restrict__ kb,
    unsigned short* __restrict__ vb)
{
    const int z = blockIdx.z;
    const unsigned short* Bhi = wt + (size_t)z * (CDIM * CDIM);
    const unsigned short* Blo = wt + (size_t)(4 + z) * (CDIM * CDIM);
    unsigned short* outb = (z == 0) ? qb : (z == 1) ? kb : vb;

    __shared__ short As[128 * 64];
    __shared__ short Bh[128 * 64];
    __shared__ short Bl[128 * 64];

    const int tid = threadIdx.x;
    const int w = tid >> 6, lane = tid & 63;
    const int g = lane >> 4, li = lane & 15;
    const int wr = w >> 1, wc = w & 1;
    const int m0 = blockIdx.x * 128;
    const int n0 = blockIdx.y * 128;

    const int ch = (tid & 7) * 8;     // k-offset of this thread's 16B chunk
    const int rw = tid >> 3;          // 0..31 row base within u-group

    f32x4 acc[4][4];
#pragma unroll
    for (int mi = 0; mi < 4; ++mi)
#pragma unroll
        for (int ni = 0; ni < 4; ++ni) acc[mi][ni] = (f32x4){0.f, 0.f, 0.f, 0.f};

    for (int kt = 0; kt < 16; ++kt) {
        const int k0 = kt * 64;
        __syncthreads();   // prev compute done before overwrite
#pragma unroll
        for (int u = 0; u < 4; ++u) {
            int row = u * 32 + rw;
            int ldsOff = u * 2048 + w * 512;   // elems; + lane*8 implicit
            gl_lds16(xb  + (size_t)(m0 + row) * CDIM + k0 + ch, (short*)As + ldsOff);
            gl_lds16(Bhi + (size_t)(n0 + row) * CDIM + k0 + ch, (short*)Bh + ldsOff);
            gl_lds16(Blo + (size_t)(n0 + row) * CDIM + k0 + ch, (short*)Bl + ldsOff);
        }
        __syncthreads();   // includes vmcnt(0) drain
#pragma unroll
        for (int ks = 0; ks < 2; ++ks) {
            bf16x8 af[4], bh[4], bl[4];
#pragma unroll
            for (int i = 0; i < 4; ++i) {
                af[i] = *(bf16x8*)&As[(wr * 64 + i * 16 + li) * 64 + ks * 32 + g * 8];
                bh[i] = *(bf16x8*)&Bh[(wc * 64 + i * 16 + li) * 64 + ks * 32 + g * 8];
                bl[i] = *(bf16x8*)&Bl[(wc * 64 + i * 16 + li) * 64 + ks * 32 + g * 8];
            }
#pragma unroll
            for (int mi = 0; mi < 4; ++mi)
#pragma unroll
                for (int ni = 0; ni < 4; ++ni) {
                    acc[mi][ni] = __builtin_amdgcn_mfma_f32_16x16x32_bf16(
                        af[mi], bh[ni], acc[mi][ni], 0, 0, 0);
                    acc[mi][ni] = __builtin_amdgcn_mfma_f32_16x16x32_bf16(
                        af[mi], bl[ni], acc[mi][ni], 0, 0, 0);
                }
        }
    }

    // epilogue: n -> (h = n>>6, d = n&63); m -> (b = m>>12, t = m&4095)
    const int hh = (n0 >> 6) + wc;
    const int bb = m0 >> 12;
    unsigned short* ob = outb + ((size_t)(bb * NHEAD + hh) * T_LEN) * HDIM;
#pragma unroll
    for (int mi = 0; mi < 4; ++mi)
#pragma unroll
        for (int reg = 0; reg < 4; ++reg) {
            int t = (m0 & 4095) + wr * 64 + mi * 16 + g * 4 + reg;
#pragma unroll
            for (int ni = 0; ni < 4; ++ni)
                ob[(size_t)t * HDIM + ni * 16 + li] = f2b(acc[mi][ni][reg]);
        }
}

// ---- output projection: out(T,B,C) fp32 = ao @ Wo ----
__global__ __launch_bounds__(256) void out_proj_mfma(
    const unsigned short* __restrict__ ao,
    const unsigned short* __restrict__ BT,   // WoT [n][k]
    float* __restrict__ out)
{
    __shared__ short As[128 * 64];
    __shared__ short Bs[128 * 64];

    const int tid = threadIdx.x;
    const int w = tid >> 6, lane = tid & 63;
    const int g = lane >> 4, li = lane & 15;
    const int wr = w >> 1, wc = w & 1;
    const int m0 = blockIdx.x * 128;
    const int n0 = blockIdx.y * 128;

    const int ch = (tid & 7) * 8;
    const int rw = tid >> 3;

    f32x4 acc[4][4];
#pragma unroll
    for (int mi = 0; mi < 4; ++mi)
#pragma unroll
        for (int ni = 0; ni < 4; ++ni) acc[mi][ni] = (f32x4){0.f, 0.f, 0.f, 0.f};

    for (int kt = 0; kt < 16; ++kt) {
        const int k0 = kt * 64;
        __syncthreads();
#pragma unroll
        for (int u = 0; u < 4; ++u) {
            int row = u * 32 + rw;
            int ldsOff = u * 2048 + w * 512;
            gl_lds16(ao + (size_t)(m0 + row) * CDIM + k0 + ch, (short*)As + ldsOff);
            gl_lds16(BT + (size_t)(n0 + row) * CDIM + k0 + ch, (short*)Bs + ldsOff);
        }
        __syncthreads();
#pragma unroll
        for (int ks = 0; ks < 2; ++ks) {
            bf16x8 af[4], bf[4];
#pragma unroll
            for (int i = 0; i < 4; ++i) {
                af[i] = *(bf16x8*)&As[(wr * 64 + i * 16 + li) * 64 + ks * 32 + g * 8];
                bf[i] = *(bf16x8*)&Bs[(wc * 64 + i * 16 + li) * 64 + ks * 32 + g * 8];
            }
#pragma unroll
            for (int mi = 0; mi < 4; ++mi)
#pragma unroll
                for (int ni = 0; ni < 4; ++ni)
                    acc[mi][ni] = __builtin_amdgcn_mfma_f32_16x16x32_bf16(
                        af[mi], bf[ni], acc[mi][ni], 0, 0, 0);
        }
    }

#pragma unroll
    for (int mi = 0; mi < 4; ++mi)
#pragma unroll
        for (int reg = 0; reg < 4; ++reg) {
            int m = m0 + wr * 64 + mi * 16 + g * 4 + reg;
            int bb = m >> 12, t = m & 4095;
            float* orow = out + ((size_t)t * BATCH + bb) * CDIM + n0 + wc * 64;
#pragma unroll
            for (int ni = 0; ni < 4; ++ni)
                orow[ni * 16 + li] = acc[mi][ni][reg];
        }
}

// ---------------- relative position bucket (== reference fp32 log formula) ----
__device__ __forceinline__ int rel_bucket(int rel) {
    int rb = (rel > 0) ? 16 : 0;
    int rp = abs(rel);
    int bu;
    if (rp < 8) bu = rp;
    else if (rp < 12) bu = 8;
    else if (rp < 16) bu = 9;
    else if (rp < 23) bu = 10;
    else if (rp < 32) bu = 11;
    else if (rp < 46) bu = 12;
    else if (rp < 64) bu = 13;
    else if (rp < 91) bu = 14;
    else bu = 15;
    return rb + bu;
}

// ---------------- MFMA attention (unchanged except ao -> bf16) ----------------
#define QS_STR 72
#define KS_STR 72
#define VT_STR 72
#define PL_STR 72

__global__ __launch_bounds__(256) void attn_mfma(
    const unsigned short* __restrict__ qb, const unsigned short* __restrict__ kb,
    const unsigned short* __restrict__ vb, const float* __restrict__ table,
    unsigned short* __restrict__ ao)
{
    const int n = blockIdx.x;
    const int h = blockIdx.y;
    const int b = blockIdx.z;
    const int tid = threadIdx.x;
    const int w = tid >> 6;
    const int lane = tid & 63;
    const int g = lane >> 4;
    const int li = lane & 15;

    __shared__ short Qs[128 * QS_STR];
    __shared__ short Ks[64 * KS_STR];
    __shared__ short Vt[64 * VT_STR];
    __shared__ short Pl[4][32 * PL_STR];
    __shared__ float ldsb[512];

    const unsigned short* qBase = qb + (((size_t)b * NHEAD + h) * T_LEN + (size_t)n * BLK) * HDIM;
    const unsigned short* kBase = kb + ((size_t)b * NHEAD + h) * T_LEN * HDIM;
    const unsigned short* vBase = vb + ((size_t)b * NHEAD + h) * T_LEN * HDIM;

    for (int i = tid; i < 512; i += 256) {
        ldsb[i] = table[rel_bucket(i - 255) * NHEAD + h];
    }
#pragma unroll
    for (int u = 0; u < 4; ++u) {
        int c = tid + u * 256;
        int row = c >> 3, ch = c & 7;
        *(bf16x8*)&Qs[row * QS_STR + ch * 8] =
            *(const bf16x8*)(qBase + (size_t)row * HDIM + ch * 8);
    }
    __syncthreads();

    bf16x8 aq[2][2];
#pragma unroll
    for (int mi = 0; mi < 2; ++mi)
#pragma unroll
        for (int ks = 0; ks < 2; ++ks)
            aq[mi][ks] = *(bf16x8*)&Qs[(w * 32 + mi * 16 + li) * QS_STR + ks * 32 + g * 8];

    f32x4 oacc[2][4];
    float m_run[2][4], l_run[2][4], scl[2][4];
#pragma unroll
    for (int mi = 0; mi < 2; ++mi)
#pragma unroll
        for (int r4 = 0; r4 < 4; ++r4) {
            oacc[mi][r4] = (f32x4){0.f, 0.f, 0.f, 0.f};
            m_run[mi][r4] = -1e30f;
            l_run[mi][r4] = 0.f;
        }

    for (int kt = 0; kt < 6; ++kt) {
        __syncthreads();
        const int tk0 = (n - 1) * BLK + kt * 64;
#pragma unroll
        for (int u = 0; u < 2; ++u) {
            int c = tid + u * 256;
            int row = c >> 3, ch = c & 7;
            int tok = tk0 + row;
            bf16x8 kv = {0, 0, 0, 0, 0, 0, 0, 0};
            bf16x8 vv = {0, 0, 0, 0, 0, 0, 0, 0};
            if (tok >= 0 && tok < T_LEN) {
                kv = *(const bf16x8*)(kBase + (size_t)tok * HDIM + ch * 8);
                vv = *(const bf16x8*)(vBase + (size_t)tok * HDIM + ch * 8);
            }
            *(bf16x8*)&Ks[row * KS_STR + ch * 8] = kv;
#pragma unroll
            for (int j = 0; j < 8; ++j)
                Vt[(ch * 8 + j) * VT_STR + row] = vv[j];
        }
        __syncthreads();

        f32x4 sacc[2][4];
#pragma unroll
        for (int mi = 0; mi < 2; ++mi)
#pragma unroll
            for (int ni = 0; ni < 4; ++ni)
                sacc[mi][ni] = (f32x4){0.f, 0.f, 0.f, 0.f};
#pragma unroll
        for (int ks = 0; ks < 2; ++ks) {
            bf16x8 bk[4];
#pragma unroll
            for (int ni = 0; ni < 4; ++ni)
                bk[ni] = *(bf16x8*)&Ks[(ni * 16 + li) * KS_STR + ks * 32 + g * 8];
#pragma unroll
            for (int mi = 0; mi < 2; ++mi)
#pragma unroll
                for (int ni = 0; ni < 4; ++ni)
                    sacc[mi][ni] = __builtin_amdgcn_mfma_f32_16x16x32_bf16(
                        aq[mi][ks], bk[ni], sacc[mi][ni], 0, 0, 0);
        }

#pragma unroll
        for (int mi = 0; mi < 2; ++mi) {
            const int rq = w * 32 + mi * 16 + g * 4;
#pragma unroll
            for (int reg = 0; reg < 4; ++reg) {
                const int r = rq + reg;
                float sv[4];
#pragma unroll
                for (int ni = 0; ni < 4; ++ni) {
                    int kk = kt * 64 + ni * 16 + li;
                    sv[ni] = sacc[mi][ni][reg] + ldsb[kk - r + 127];
                }
                float tm = fmaxf(fmaxf(sv[0], sv[1]), fmaxf(sv[2], sv[3]));
                tm = fmaxf(tm, __shfl_xor(tm, 1));
                tm = fmaxf(tm, __shfl_xor(tm, 2));
                tm = fmaxf(tm, __shfl_xor(tm, 4));
                tm = fmaxf(tm, __shfl_xor(tm, 8));
                float mold = m_run[mi][reg];
                float mnew = fmaxf(mold, tm);
                float sc = __expf(mold - mnew);
                float ps = 0.f;
                unsigned short pb[4];
#pragma unroll
                for (int ni = 0; ni < 4; ++ni) {
                    float pv = __expf(sv[ni] - mnew);
                    ps += pv;
                    pb[ni] = f2b(pv);
                }
                ps += __shfl_xor(ps, 1);
                ps += __shfl_xor(ps, 2);
                ps += __shfl_xor(ps, 4);
                ps += __shfl_xor(ps, 8);
                l_run[mi][reg] = l_run[mi][reg] * sc + ps;
                m_run[mi][reg] = mnew;
                scl[mi][reg] = sc;
#pragma unroll
                for (int ni = 0; ni < 4; ++ni)
                    Pl[w][(mi * 16 + g * 4 + reg) * PL_STR + ni * 16 + li] = (short)pb[ni];
            }
        }
#pragma unroll
        for (int mi = 0; mi < 2; ++mi)
#pragma unroll
            for (int dn = 0; dn < 4; ++dn)
#pragma unroll
                for (int reg = 0; reg < 4; ++reg)
                    oacc[mi][dn][reg] *= scl[mi][reg];

        __syncthreads();

#pragma unroll
        for (int ks = 0; ks < 2; ++ks) {
            bf16x8 ap[2], bv[4];
#pragma unroll
            for (int mi = 0; mi < 2; ++mi)
                ap[mi] = *(bf16x8*)&Pl[w][(mi * 16 + li) * PL_STR + ks * 32 + g * 8];
#pragma unroll
            for (int dn = 0; dn < 4; ++dn)
                bv[dn] = *(bf16x8*)&Vt[(dn * 16 + li) * VT_STR + ks * 32 + g * 8];
#pragma unroll
            for (int mi = 0; mi < 2; ++mi)
#pragma unroll
                for (int dn = 0; dn < 4; ++dn)
                    oacc[mi][dn] = __builtin_amdgcn_mfma_f32_16x16x32_bf16(
                        ap[mi], bv[dn], oacc[mi][dn], 0, 0, 0);
        }
    }

#pragma unroll
    for (int mi = 0; mi < 2; ++mi) {
#pragma unroll
        for (int reg = 0; reg < 4; ++reg) {
            float inv = 1.f / l_run[mi][reg];
            int t = n * BLK + w * 32 + mi * 16 + g * 4 + reg;
            unsigned short* orow = ao + ((size_t)b * T_LEN + t) * CDIM + h * HDIM;
#pragma unroll
            for (int dn = 0; dn < 4; ++dn)
                orow[dn * 16 + li] = f2b(oacc[mi][dn][reg] * inv);
        }
    }
}

extern "C" void kernel_launch(void* const* d_in, const int* in_sizes, int n_in,
                              void* d_out, int out_size, void* d_ws, size_t ws_size,
                              hipStream_t stream) {
    const float* hidden = (const float*)d_in[0];
    const float* Wq = (const float*)d_in[1];
    const float* Wk = (const float*)d_in[2];
    const float* Wv = (const float*)d_in[3];
    const float* Wo = (const float*)d_in[4];
    const float* table = (const float*)d_in[5];
    float* out = (float*)d_out;

    const size_t qkvElems = (size_t)BATCH * NHEAD * T_LEN * HDIM;   // 16.78M
    const size_t wElems = (size_t)CDIM * CDIM;                      // 1.05M
    // qb,kb,vb + xb(=ao) bf16 + 7 weight matrices bf16 = ~142 MiB
    const size_t needed = (4 * qkvElems + 7 * wElems) * 2;
    if (ws_size < needed) return;

    unsigned short* qb = (unsigned short*)d_ws;
    unsigned short* kb = qb + qkvElems;
    unsigned short* vb = kb + qkvElems;
    unsigned short* xb = vb + qkvElems;     // reused as ao after proj
    unsigned short* wt = xb + qkvElems;     // 7 x 1M elems

    conv_w<<<dim3(32, 32, 4), 256, 0, stream>>>(Wq, Wk, Wv, Wo, wt);
    conv_x<<<8192, 256, 0, stream>>>(hidden, xb);
    proj_mfma<<<dim3(128, 8, 3), 256, 0, stream>>>(xb, wt, qb, kb, vb);
    attn_mfma<<<dim3(NBLK, NHEAD, BATCH), 256, 0, stream>>>(qb, kb, vb, table, xb);
    out_proj_mfma<<<dim3(128, 8), 256, 0, stream>>>(xb, wt + 3 * wElems, out);
}

// Round 5
// 353.155 us; speedup vs baseline: 50.8767x; 1.0986x over previous
//
#include <hip/hip_runtime.h>
#include <hip/hip_bf16.h>

// LocalAttention (T5-style blocked local attention).
// T=4096, B=4, C=1024, H=16, D=64, L=128, NB=32, window = 3 blocks = 384 keys.
//
// Round 4: dropped the W hi+lo compensation (round-3 evidence: Wo was plain
// bf16 and absmax stayed at 0.0039 == all-fp32 round-1 value, so W-bf16
// rounding is not the dominant error term). Halves proj MFMA work; LDS
// 48->32KB raises occupancy. proj at ~900 TF effective == m97 ceiling.

#define T_LEN 4096
#define BATCH 4
#define CDIM 1024
#define NHEAD 16
#define HDIM 64
#define BLK 128
#define NBLK 32

typedef __attribute__((ext_vector_type(8))) short bf16x8;
typedef __attribute__((ext_vector_type(4))) float f32x4;

__device__ __forceinline__ unsigned short f2b(float f) {
    __hip_bfloat16 h = __float2bfloat16(f);
    return *reinterpret_cast<unsigned short*>(&h);
}
__device__ __forceinline__ void gl_lds16(const void* g, void* l) {
    __builtin_amdgcn_global_load_lds(
        (const __attribute__((address_space(1))) unsigned int*)g,
        (__attribute__((address_space(3))) unsigned int*)l, 16, 0, 0);
}

// ---- convert x: hidden (T,B,C) fp32 -> xb bf16 [m=b*T+t][k=c] ----
__global__ __launch_bounds__(256) void conv_x(const float* __restrict__ hidden,
                                              unsigned short* __restrict__ xb) {
    int chunk = blockIdx.x * 256 + threadIdx.x;
    int c8 = chunk & 127;
    int rem = chunk >> 7;                          // = t*4 + b
    int b = rem & 3;
    int t = rem >> 2;
    const float* src = hidden + ((size_t)rem << 10) + c8 * 8;
    float4 v0 = *(const float4*)src;
    float4 v1 = *(const float4*)(src + 4);
    bf16x8 o;
    o[0] = (short)f2b(v0.x); o[1] = (short)f2b(v0.y);
    o[2] = (short)f2b(v0.z); o[3] = (short)f2b(v0.w);
    o[4] = (short)f2b(v1.x); o[5] = (short)f2b(v1.y);
    o[6] = (short)f2b(v1.z); o[7] = (short)f2b(v1.w);
    *(bf16x8*)&xb[((size_t)(b * T_LEN + t) << 10) + c8 * 8] = o;
}

// ---- convert + transpose weights -> wt: [WqT,WkT,WvT,WoT], each [n][k] bf16.
// Wq pre-scaled by 0.125 (exact pow2).
__global__ __launch_bounds__(256) void conv_w(
    const float* __restrict__ W0, const float* __restrict__ W1,
    const float* __restrict__ W2, const float* __restrict__ W3,
    unsigned short* __restrict__ wt)
{
    const int z = blockIdx.z;
    const float* W = (z == 0) ? W0 : (z == 1) ? W1 : (z == 2) ? W2 : W3;
    const float scale = (z == 0) ? 0.125f : 1.0f;
    unsigned short* hi = wt + (size_t)z * (CDIM * CDIM);
    __shared__ float tile[32][33];
    const int r = threadIdx.x >> 5;   // 0..7
    const int c = threadIdx.x & 31;
    const int k0 = blockIdx.x * 32;
    const int n0 = blockIdx.y * 32;
#pragma unroll
    for (int i = 0; i < 4; ++i)
        tile[r + i * 8][c] = W[(size_t)(k0 + r + i * 8) * CDIM + n0 + c] * scale;
    __syncthreads();
#pragma unroll
    for (int i = 0; i < 4; ++i) {
        int nn = r + i * 8;
        hi[(size_t)(n0 + nn) * CDIM + k0 + c] = f2b(tile[c][nn]);
    }
}

// ---- projection GEMM: out = xb @ W^T, MFMA bf16, 128x128 tile, BK=64 ----
// grid (128, 8, 3), 256 threads = 4 waves (2x2).
__global__ __launch_bounds__(256) void proj_mfma(
    const unsigned short* __restrict__ xb,
    const unsigned short* __restrict__ wt,
    unsigned short* __restrict__ qb, unsigned short* __restrict__ kb,
    unsigned short* __restrict__ vb)
{
    const int z = blockIdx.z;
    const unsigned short* Bt = wt + (size_t)z * (CDIM * CDIM);
    unsigned short* outb = (z == 0) ? qb : (z == 1) ? kb : vb;

    __shared__ short As[128 * 64];
    __shared__ short Bs[128 * 64];

    const int tid = threadIdx.x;
    const int w = tid >> 6, lane = tid & 63;
    const int g = lane >> 4, li = lane & 15;
    const int wr = w >> 1, wc = w & 1;
    const int m0 = blockIdx.x * 128;
    const int n0 = blockIdx.y * 128;

    const int ch = (tid & 7) * 8;
    const int rw = tid >> 3;

    f32x4 acc[4][4];
#pragma unroll
    for (int mi = 0; mi < 4; ++mi)
#pragma unroll
        for (int ni = 0; ni < 4; ++ni) acc[mi][ni] = (f32x4){0.f, 0.f, 0.f, 0.f};

    for (int kt = 0; kt < 16; ++kt) {
        const int k0 = kt * 64;
        __syncthreads();
#pragma unroll
        for (int u = 0; u < 4; ++u) {
            int row = u * 32 + rw;
            int ldsOff = u * 2048 + w * 512;
            gl_lds16(xb + (size_t)(m0 + row) * CDIM + k0 + ch, (short*)As + ldsOff);
            gl_lds16(Bt + (size_t)(n0 + row) * CDIM + k0 + ch, (short*)Bs + ldsOff);
        }
        __syncthreads();
#pragma unroll
        for (int ks = 0; ks < 2; ++ks) {
            bf16x8 af[4], bf[4];
#pragma unroll
            for (int i = 0; i < 4; ++i) {
                af[i] = *(bf16x8*)&As[(wr * 64 + i * 16 + li) * 64 + ks * 32 + g * 8];
                bf[i] = *(bf16x8*)&Bs[(wc * 64 + i * 16 + li) * 64 + ks * 32 + g * 8];
            }
#pragma unroll
            for (int mi = 0; mi < 4; ++mi)
#pragma unroll
                for (int ni = 0; ni < 4; ++ni)
                    acc[mi][ni] = __builtin_amdgcn_mfma_f32_16x16x32_bf16(
                        af[mi], bf[ni], acc[mi][ni], 0, 0, 0);
        }
    }

    // epilogue: n -> (h = n>>6, d = n&63); m -> (b = m>>12, t = m&4095)
    const int hh = (n0 >> 6) + wc;
    const int bb = m0 >> 12;
    unsigned short* ob = outb + ((size_t)(bb * NHEAD + hh) * T_LEN) * HDIM;
#pragma unroll
    for (int mi = 0; mi < 4; ++mi)
#pragma unroll
        for (int reg = 0; reg < 4; ++reg) {
            int t = (m0 & 4095) + wr * 64 + mi * 16 + g * 4 + reg;
#pragma unroll
            for (int ni = 0; ni < 4; ++ni)
                ob[(size_t)t * HDIM + ni * 16 + li] = f2b(acc[mi][ni][reg]);
        }
}

// ---- output projection: out(T,B,C) fp32 = ao @ Wo ----
__global__ __launch_bounds__(256) void out_proj_mfma(
    const unsigned short* __restrict__ ao,
    const unsigned short* __restrict__ BT,   // WoT [n][k]
    float* __restrict__ out)
{
    __shared__ short As[128 * 64];
    __shared__ short Bs[128 * 64];

    const int tid = threadIdx.x;
    const int w = tid >> 6, lane = tid & 63;
    const int g = lane >> 4, li = lane & 15;
    const int wr = w >> 1, wc = w & 1;
    const int m0 = blockIdx.x * 128;
    const int n0 = blockIdx.y * 128;

    const int ch = (tid & 7) * 8;
    const int rw = tid >> 3;

    f32x4 acc[4][4];
#pragma unroll
    for (int mi = 0; mi < 4; ++mi)
#pragma unroll
        for (int ni = 0; ni < 4; ++ni) acc[mi][ni] = (f32x4){0.f, 0.f, 0.f, 0.f};

    for (int kt = 0; kt < 16; ++kt) {
        const int k0 = kt * 64;
        __syncthreads();
#pragma unroll
        for (int u = 0; u < 4; ++u) {
            int row = u * 32 + rw;
            int ldsOff = u * 2048 + w * 512;
            gl_lds16(ao + (size_t)(m0 + row) * CDIM + k0 + ch, (short*)As + ldsOff);
            gl_lds16(BT + (size_t)(n0 + row) * CDIM + k0 + ch, (short*)Bs + ldsOff);
        }
        __syncthreads();
#pragma unroll
        for (int ks = 0; ks < 2; ++ks) {
            bf16x8 af[4], bf[4];
#pragma unroll
            for (int i = 0; i < 4; ++i) {
                af[i] = *(bf16x8*)&As[(wr * 64 + i * 16 + li) * 64 + ks * 32 + g * 8];
                bf[i] = *(bf16x8*)&Bs[(wc * 64 + i * 16 + li) * 64 + ks * 32 + g * 8];
            }
#pragma unroll
            for (int mi = 0; mi < 4; ++mi)
#pragma unroll
                for (int ni = 0; ni < 4; ++ni)
                    acc[mi][ni] = __builtin_amdgcn_mfma_f32_16x16x32_bf16(
                        af[mi], bf[ni], acc[mi][ni], 0, 0, 0);
        }
    }

#pragma unroll
    for (int mi = 0; mi < 4; ++mi)
#pragma unroll
        for (int reg = 0; reg < 4; ++reg) {
            int m = m0 + wr * 64 + mi * 16 + g * 4 + reg;
            int bb = m >> 12, t = m & 4095;
            float* orow = out + ((size_t)t * BATCH + bb) * CDIM + n0 + wc * 64;
#pragma unroll
            for (int ni = 0; ni < 4; ++ni)
                orow[ni * 16 + li] = acc[mi][ni][reg];
        }
}

// ---------------- relative position bucket (== reference fp32 log formula) ----
__device__ __forceinline__ int rel_bucket(int rel) {
    int rb = (rel > 0) ? 16 : 0;
    int rp = abs(rel);
    int bu;
    if (rp < 8) bu = rp;
    else if (rp < 12) bu = 8;
    else if (rp < 16) bu = 9;
    else if (rp < 23) bu = 10;
    else if (rp < 32) bu = 11;
    else if (rp < 46) bu = 12;
    else if (rp < 64) bu = 13;
    else if (rp < 91) bu = 14;
    else bu = 15;
    return rb + bu;
}

// ---------------- MFMA attention ----------------
#define QS_STR 72
#define KS_STR 72
#define VT_STR 72
#define PL_STR 72

__global__ __launch_bounds__(256) void attn_mfma(
    const unsigned short* __restrict__ qb, const unsigned short* __restrict__ kb,
    const unsigned short* __restrict__ vb, const float* __restrict__ table,
    unsigned short* __restrict__ ao)
{
    const int n = blockIdx.x;
    const int h = blockIdx.y;
    const int b = blockIdx.z;
    const int tid = threadIdx.x;
    const int w = tid >> 6;
    const int lane = tid & 63;
    const int g = lane >> 4;
    const int li = lane & 15;

    __shared__ short Qs[128 * QS_STR];
    __shared__ short Ks[64 * KS_STR];
    __shared__ short Vt[64 * VT_STR];
    __shared__ short Pl[4][32 * PL_STR];
    __shared__ float ldsb[512];

    const unsigned short* qBase = qb + (((size_t)b * NHEAD + h) * T_LEN + (size_t)n * BLK) * HDIM;
    const unsigned short* kBase = kb + ((size_t)b * NHEAD + h) * T_LEN * HDIM;
    const unsigned short* vBase = vb + ((size_t)b * NHEAD + h) * T_LEN * HDIM;

    for (int i = tid; i < 512; i += 256) {
        ldsb[i] = table[rel_bucket(i - 255) * NHEAD + h];
    }
#pragma unroll
    for (int u = 0; u < 4; ++u) {
        int c = tid + u * 256;
        int row = c >> 3, ch = c & 7;
        *(bf16x8*)&Qs[row * QS_STR + ch * 8] =
            *(const bf16x8*)(qBase + (size_t)row * HDIM + ch * 8);
    }
    __syncthreads();

    bf16x8 aq[2][2];
#pragma unroll
    for (int mi = 0; mi < 2; ++mi)
#pragma unroll
        for (int ks = 0; ks < 2; ++ks)
            aq[mi][ks] = *(bf16x8*)&Qs[(w * 32 + mi * 16 + li) * QS_STR + ks * 32 + g * 8];

    f32x4 oacc[2][4];
    float m_run[2][4], l_run[2][4], scl[2][4];
#pragma unroll
    for (int mi = 0; mi < 2; ++mi)
#pragma unroll
        for (int r4 = 0; r4 < 4; ++r4) {
            oacc[mi][r4] = (f32x4){0.f, 0.f, 0.f, 0.f};
            m_run[mi][r4] = -1e30f;
            l_run[mi][r4] = 0.f;
        }

    for (int kt = 0; kt < 6; ++kt) {
        __syncthreads();
        const int tk0 = (n - 1) * BLK + kt * 64;
#pragma unroll
        for (int u = 0; u < 2; ++u) {
            int c = tid + u * 256;
            int row = c >> 3, ch = c & 7;
            int tok = tk0 + row;
            bf16x8 kv = {0, 0, 0, 0, 0, 0, 0, 0};
            bf16x8 vv = {0, 0, 0, 0, 0, 0, 0, 0};
            if (tok >= 0 && tok < T_LEN) {
                kv = *(const bf16x8*)(kBase + (size_t)tok * HDIM + ch * 8);
                vv = *(const bf16x8*)(vBase + (size_t)tok * HDIM + ch * 8);
            }
            *(bf16x8*)&Ks[row * KS_STR + ch * 8] = kv;
#pragma unroll
            for (int j = 0; j < 8; ++j)
                Vt[(ch * 8 + j) * VT_STR + row] = vv[j];
        }
        __syncthreads();

        f32x4 sacc[2][4];
#pragma unroll
        for (int mi = 0; mi < 2; ++mi)
#pragma unroll
            for (int ni = 0; ni < 4; ++ni)
                sacc[mi][ni] = (f32x4){0.f, 0.f, 0.f, 0.f};
#pragma unroll
        for (int ks = 0; ks < 2; ++ks) {
            bf16x8 bk[4];
#pragma unroll
            for (int ni = 0; ni < 4; ++ni)
                bk[ni] = *(bf16x8*)&Ks[(ni * 16 + li) * KS_STR + ks * 32 + g * 8];
#pragma unroll
            for (int mi = 0; mi < 2; ++mi)
#pragma unroll
                for (int ni = 0; ni < 4; ++ni)
                    sacc[mi][ni] = __builtin_amdgcn_mfma_f32_16x16x32_bf16(
                        aq[mi][ks], bk[ni], sacc[mi][ni], 0, 0, 0);
        }

#pragma unroll
        for (int mi = 0; mi < 2; ++mi) {
            const int rq = w * 32 + mi * 16 + g * 4;
#pragma unroll
            for (int reg = 0; reg < 4; ++reg) {
                const int r = rq + reg;
                float sv[4];
#pragma unroll
                for (int ni = 0; ni < 4; ++ni) {
                    int kk = kt * 64 + ni * 16 + li;
                    sv[ni] = sacc[mi][ni][reg] + ldsb[kk - r + 127];
                }
                float tm = fmaxf(fmaxf(sv[0], sv[1]), fmaxf(sv[2], sv[3]));
                tm = fmaxf(tm, __shfl_xor(tm, 1));
                tm = fmaxf(tm, __shfl_xor(tm, 2));
                tm = fmaxf(tm, __shfl_xor(tm, 4));
                tm = fmaxf(tm, __shfl_xor(tm, 8));
                float mold = m_run[mi][reg];
                float mnew = fmaxf(mold, tm);
                float sc = __expf(mold - mnew);
                float ps = 0.f;
                unsigned short pb[4];
#pragma unroll
                for (int ni = 0; ni < 4; ++ni) {
                    float pv = __expf(sv[ni] - mnew);
                    ps += pv;
                    pb[ni] = f2b(pv);
                }
                ps += __shfl_xor(ps, 1);
                ps += __shfl_xor(ps, 2);
                ps += __shfl_xor(ps, 4);
                ps += __shfl_xor(ps, 8);
                l_run[mi][reg] = l_run[mi][reg] * sc + ps;
                m_run[mi][reg] = mnew;
                scl[mi][reg] = sc;
#pragma unroll
                for (int ni = 0; ni < 4; ++ni)
                    Pl[w][(mi * 16 + g * 4 + reg) * PL_STR + ni * 16 + li] = (short)pb[ni];
            }
        }
#pragma unroll
        for (int mi = 0; mi < 2; ++mi)
#pragma unroll
            for (int dn = 0; dn < 4; ++dn)
#pragma unroll
                for (int reg = 0; reg < 4; ++reg)
                    oacc[mi][dn][reg] *= scl[mi][reg];

        __syncthreads();

#pragma unroll
        for (int ks = 0; ks < 2; ++ks) {
            bf16x8 ap[2], bv[4];
#pragma unroll
            for (int mi = 0; mi < 2; ++mi)
                ap[mi] = *(bf16x8*)&Pl[w][(mi * 16 + li) * PL_STR + ks * 32 + g * 8];
#pragma unroll
            for (int dn = 0; dn < 4; ++dn)
                bv[dn] = *(bf16x8*)&Vt[(dn * 16 + li) * VT_STR + ks * 32 + g * 8];
#pragma unroll
            for (int mi = 0; mi < 2; ++mi)
#pragma unroll
                for (int dn = 0; dn < 4; ++dn)
                    oacc[mi][dn] = __builtin_amdgcn_mfma_f32_16x16x32_bf16(
                        ap[mi], bv[dn], oacc[mi][dn], 0, 0, 0);
        }
    }

#pragma unroll
    for (int mi = 0; mi < 2; ++mi) {
#pragma unroll
        for (int reg = 0; reg < 4; ++reg) {
            float inv = 1.f / l_run[mi][reg];
            int t = n * BLK + w * 32 + mi * 16 + g * 4 + reg;
            unsigned short* orow = ao + ((size_t)b * T_LEN + t) * CDIM + h * HDIM;
#pragma unroll
            for (int dn = 0; dn < 4; ++dn)
                orow[dn * 16 + li] = f2b(oacc[mi][dn][reg] * inv);
        }
    }
}

extern "C" void kernel_launch(void* const* d_in, const int* in_sizes, int n_in,
                              void* d_out, int out_size, void* d_ws, size_t ws_size,
                              hipStream_t stream) {
    const float* hidden = (const float*)d_in[0];
    const float* Wq = (const float*)d_in[1];
    const float* Wk = (const float*)d_in[2];
    const float* Wv = (const float*)d_in[3];
    const float* Wo = (const float*)d_in[4];
    const float* table = (const float*)d_in[5];
    float* out = (float*)d_out;

    const size_t qkvElems = (size_t)BATCH * NHEAD * T_LEN * HDIM;   // 16.78M
    const size_t wElems = (size_t)CDIM * CDIM;                      // 1.05M
    const size_t needed = (4 * qkvElems + 4 * wElems) * 2;          // ~136 MiB
    if (ws_size < needed) return;

    unsigned short* qb = (unsigned short*)d_ws;
    unsigned short* kb = qb + qkvElems;
    unsigned short* vb = kb + qkvElems;
    unsigned short* xb = vb + qkvElems;     // reused as ao after proj
    unsigned short* wt = xb + qkvElems;     // 4 x 1M elems

    conv_w<<<dim3(32, 32, 4), 256, 0, stream>>>(Wq, Wk, Wv, Wo, wt);
    conv_x<<<8192, 256, 0, stream>>>(hidden, xb);
    proj_mfma<<<dim3(128, 8, 3), 256, 0, stream>>>(xb, wt, qb, kb, vb);
    attn_mfma<<<dim3(NBLK, NHEAD, BATCH), 256, 0, stream>>>(qb, kb, vb, table, xb);
    out_proj_mfma<<<dim3(128, 8), 256, 0, stream>>>(xb, wt + 3 * wElems, out);
}

// Round 6
// 272.552 us; speedup vs baseline: 65.9228x; 1.2957x over previous
//
#include <hip/hip_runtime.h>
#include <hip/hip_bf16.h>

// LocalAttention (T5-style blocked local attention).
// T=4096, B=4, C=1024, H=16, D=64, L=128, NB=32, window = 3 blocks = 384 keys.
//
// Round 5: projections + out_proj moved to an 8-phase 256x256 deep-pipelined
// MFMA GEMM (T2 swizzle + T3/T4 counted-vmcnt phases + T5 setprio). Round-4
// evidence: 2-barrier loop is drain-bound (MfmaUtil 26%, 600 TF eff).
// Schedule (iteration i computes K-tiles e=2i in buf0, o=2i+1 in buf1):
//   P0: LDB(e)+LDA(q0) | stage A0(o)   | MFMA q0
//   P1: LDA(q1)        | stage A1(o)   | MFMA q1
//   P2: LDA(q2)        | stage B0(e+2) | MFMA q2
//   P3: LDA(q3)        | stage B1(e+2) | MFMA q3 | vmcnt(4) barrier
//   P4-P7: same on o, staging A0/A1(e+2), B0/B1(o+2) | vmcnt(4)
// Liveness verified: B(t) dead after its P0/P4 (held in regs); A-halves dead
// after q3; every stage-issue separated from last reader by >=1 barrier;
// drains cover each tile fully before first read. Last iter: vmcnt(0).

#define T_LEN 4096
#define BATCH 4
#define CDIM 1024
#define NHEAD 16
#define HDIM 64
#define BLK 128
#define NBLK 32

typedef __attribute__((ext_vector_type(8))) short bf16x8;
typedef __attribute__((ext_vector_type(4))) float f32x4;

__device__ __forceinline__ unsigned short f2b(float f) {
    __hip_bfloat16 h = __float2bfloat16(f);
    return *reinterpret_cast<unsigned short*>(&h);
}
__device__ __forceinline__ void gl_lds16(const void* g, void* l) {
    __builtin_amdgcn_global_load_lds(
        (const __attribute__((address_space(1))) unsigned int*)g,
        (__attribute__((address_space(3))) unsigned int*)l, 16, 0, 0);
}

// ---- convert x: hidden (T,B,C) fp32 -> xb bf16 [m=b*T+t][k=c] ----
__global__ __launch_bounds__(256) void conv_x(const float* __restrict__ hidden,
                                              unsigned short* __restrict__ xb) {
    int chunk = blockIdx.x * 256 + threadIdx.x;
    int c8 = chunk & 127;
    int rem = chunk >> 7;                          // = t*4 + b
    int b = rem & 3;
    int t = rem >> 2;
    const float* src = hidden + ((size_t)rem << 10) + c8 * 8;
    float4 v0 = *(const float4*)src;
    float4 v1 = *(const float4*)(src + 4);
    bf16x8 o;
    o[0] = (short)f2b(v0.x); o[1] = (short)f2b(v0.y);
    o[2] = (short)f2b(v0.z); o[3] = (short)f2b(v0.w);
    o[4] = (short)f2b(v1.x); o[5] = (short)f2b(v1.y);
    o[6] = (short)f2b(v1.z); o[7] = (short)f2b(v1.w);
    *(bf16x8*)&xb[((size_t)(b * T_LEN + t) << 10) + c8 * 8] = o;
}

// ---- convert + transpose weights -> wt: [WqT,WkT,WvT,WoT], each [n][k] bf16.
__global__ __launch_bounds__(256) void conv_w(
    const float* __restrict__ W0, const float* __restrict__ W1,
    const float* __restrict__ W2, const float* __restrict__ W3,
    unsigned short* __restrict__ wt)
{
    const int z = blockIdx.z;
    const float* W = (z == 0) ? W0 : (z == 1) ? W1 : (z == 2) ? W2 : W3;
    const float scale = (z == 0) ? 0.125f : 1.0f;
    unsigned short* hi = wt + (size_t)z * (CDIM * CDIM);
    __shared__ float tile[32][33];
    const int r = threadIdx.x >> 5;   // 0..7
    const int c = threadIdx.x & 31;
    const int k0 = blockIdx.x * 32;
    const int n0 = blockIdx.y * 32;
#pragma unroll
    for (int i = 0; i < 4; ++i)
        tile[r + i * 8][c] = W[(size_t)(k0 + r + i * 8) * CDIM + n0 + c] * scale;
    __syncthreads();
#pragma unroll
    for (int i = 0; i < 4; ++i) {
        int nn = r + i * 8;
        hi[(size_t)(n0 + nn) * CDIM + k0 + c] = f2b(tile[c][nn]);
    }
}

// ================= 8-phase 256x256 GEMM (bf16 MFMA) =================
// MODE 0: fused qkv projection. A = xb [16384][1024], B = wt [3072][1024],
//         epilogue scatters bf16 to qb/kb/vb [B][H][T][D].
// MODE 1: out_proj. A = ao [16384][1024], B = WoT [1024][1024],
//         epilogue writes fp32 out (T,B,C)-transposed.

#define STAGE(pb, tau, half, isB) do {                                         \
    const unsigned short* _gb = (isB) ? Bg : Ag;                               \
    const int _bo = (pb) * 32768 + (isB) * 16384 + (half) * 8192;              \
    gl_lds16(_gb + (size_t)((half) * 128 + sr) * 1024 + (tau) * 64,            \
             (short*)lds + _bo + ldsW);                                        \
    gl_lds16(_gb + (size_t)((half) * 128 + 64 + sr) * 1024 + (tau) * 64,       \
             (short*)lds + _bo + 4096 + ldsW);                                 \
} while (0)

#define LDB(p) do {                                                            \
    _Pragma("unroll") for (int nr = 0; nr < 4; ++nr) {                         \
        int _row = wc * 64 + nr * 16 + li;                                     \
        _Pragma("unroll") for (int ks = 0; ks < 2; ++ks)                       \
            bkf[nr][ks] = *(const bf16x8*)(ldsc + (p) * 65536 + 32768 +        \
                ((_row * 128 + ks * 64 + g * 16) ^ swz));                      \
    } } while (0)

#define LDA(p, q) do {                                                         \
    _Pragma("unroll") for (int dm = 0; dm < 2; ++dm) {                         \
        int _row = wr * 128 + ((q) * 2 + dm) * 16 + li;                        \
        _Pragma("unroll") for (int ks = 0; ks < 2; ++ks)                       \
            af[dm][ks] = *(const bf16x8*)(ldsc + (p) * 65536 +                 \
                ((_row * 128 + ks * 64 + g * 16) ^ swz));                      \
    } } while (0)

#define MM(q) do {                                                             \
    _Pragma("unroll") for (int dm = 0; dm < 2; ++dm)                           \
    _Pragma("unroll") for (int nr = 0; nr < 4; ++nr) {                         \
        acc[(q)*2+dm][nr] = __builtin_amdgcn_mfma_f32_16x16x32_bf16(           \
            af[dm][0], bkf[nr][0], acc[(q)*2+dm][nr], 0, 0, 0);                \
        acc[(q)*2+dm][nr] = __builtin_amdgcn_mfma_f32_16x16x32_bf16(           \
            af[dm][1], bkf[nr][1], acc[(q)*2+dm][nr], 0, 0, 0);                \
    } } while (0)

#define MID() do {                                                             \
    __builtin_amdgcn_s_barrier();                                              \
    asm volatile("s_waitcnt lgkmcnt(0)" ::: "memory");                         \
    __builtin_amdgcn_sched_barrier(0);                                         \
    __builtin_amdgcn_s_setprio(1);                                             \
} while (0)

#define TAIL() do {                                                            \
    __builtin_amdgcn_s_setprio(0);                                             \
    __builtin_amdgcn_sched_barrier(0);                                         \
    __builtin_amdgcn_s_barrier();                                              \
} while (0)

template<int MODE>
__global__ __launch_bounds__(512, 1) void gemm_8ph(
    const unsigned short* __restrict__ Am,
    const unsigned short* __restrict__ Bm,
    unsigned short* __restrict__ qb, unsigned short* __restrict__ kb,
    unsigned short* __restrict__ vb, float* __restrict__ fout)
{
    __shared__ short lds[65536];   // 128 KB: [buf:2][A 256x64 | B 256x64]

    const int tid = threadIdx.x;
    const int w = tid >> 6, lane = tid & 63;
    const int g = lane >> 4, li = lane & 15;
    const int wr = w >> 2, wc = w & 3;           // 2 x 4 wave grid
    const int m0 = blockIdx.x * 256;
    const int n0 = blockIdx.y * 256;

    // staging: thread covers 16B chunk; linear LDS dest, inverse-swizzled src
    const int sr = tid >> 3;                       // 0..63
    const int cbs = ((tid & 7) * 16) ^ ((sr & 7) << 4);
    const int ldsW = w * 512;                      // shorts (wave-uniform)
    const unsigned short* Ag = Am + (size_t)m0 * 1024 + (cbs >> 1);
    const unsigned short* Bg = Bm + (size_t)n0 * 1024 + (cbs >> 1);

    const char* ldsc = (const char*)lds;
    const int swz = (li & 7) << 4;

    f32x4 acc[8][4];
#pragma unroll
    for (int a = 0; a < 8; ++a)
#pragma unroll
        for (int b = 0; b < 4; ++b) acc[a][b] = (f32x4){0.f, 0.f, 0.f, 0.f};

    bf16x8 bkf[4][2];
    bf16x8 af[2][2];

    // prologue: tile0 fully + B halves of tile1; drain tile0 (4 loads left)
    STAGE(0, 0, 0, 0); STAGE(0, 0, 1, 0);
    STAGE(0, 0, 0, 1); STAGE(0, 0, 1, 1);
    STAGE(1, 1, 0, 1); STAGE(1, 1, 1, 1);
    asm volatile("s_waitcnt vmcnt(4)" ::: "memory");
    __builtin_amdgcn_s_barrier();

#pragma unroll 1
    for (int i = 0; i < 8; ++i) {
        const int o = 2 * i + 1, e2 = 2 * i + 2, o2 = 2 * i + 3;
        const bool pf = (i < 7);
        // ---- even tile (buf0) ----
        LDB(0); LDA(0, 0); STAGE(1, o, 0, 0); MID(); MM(0); TAIL();
        LDA(0, 1); STAGE(1, o, 1, 0); MID(); MM(1); TAIL();
        LDA(0, 2); if (pf) STAGE(0, e2, 0, 1); MID(); MM(2); TAIL();
        LDA(0, 3); if (pf) STAGE(0, e2, 1, 1); MID(); MM(3);
        __builtin_amdgcn_s_setprio(0);
        __builtin_amdgcn_sched_barrier(0);
        if (pf) asm volatile("s_waitcnt vmcnt(4)" ::: "memory");
        else    asm volatile("s_waitcnt vmcnt(0)" ::: "memory");
        __builtin_amdgcn_s_barrier();
        // ---- odd tile (buf1) ----
        LDB(1); LDA(1, 0); if (pf) STAGE(0, e2, 0, 0); MID(); MM(0); TAIL();
        LDA(1, 1); if (pf) STAGE(0, e2, 1, 0); MID(); MM(1); TAIL();
        LDA(1, 2); if (pf) STAGE(1, o2, 0, 1); MID(); MM(2); TAIL();
        LDA(1, 3); if (pf) STAGE(1, o2, 1, 1); MID(); MM(3);
        __builtin_amdgcn_s_setprio(0);
        __builtin_amdgcn_sched_barrier(0);
        if (pf) asm volatile("s_waitcnt vmcnt(4)" ::: "memory");
        else    asm volatile("s_waitcnt vmcnt(0)" ::: "memory");
        __builtin_amdgcn_s_barrier();
    }

    if (MODE == 0) {
        const int nA = n0 + wc * 64;
        const int z = nA >> 10;
        const int hh = (nA & 1023) >> 6;
        unsigned short* ob = (z == 0) ? qb : (z == 1) ? kb : vb;
#pragma unroll
        for (int mr = 0; mr < 8; ++mr)
#pragma unroll
            for (int reg = 0; reg < 4; ++reg) {
                int m = m0 + wr * 128 + mr * 16 + g * 4 + reg;
                size_t ro = ((size_t)((m >> 12) * NHEAD + hh) * T_LEN + (m & 4095)) * HDIM;
#pragma unroll
                for (int nr = 0; nr < 4; ++nr)
                    ob[ro + nr * 16 + li] = f2b(acc[mr][nr][reg]);
            }
    } else {
#pragma unroll
        for (int mr = 0; mr < 8; ++mr)
#pragma unroll
            for (int reg = 0; reg < 4; ++reg) {
                int m = m0 + wr * 128 + mr * 16 + g * 4 + reg;
                float* orow = fout + ((size_t)(m & 4095) * BATCH + (m >> 12)) * CDIM
                              + n0 + wc * 64;
#pragma unroll
                for (int nr = 0; nr < 4; ++nr)
                    orow[nr * 16 + li] = acc[mr][nr][reg];
            }
    }
}

// ---------------- relative position bucket (== reference fp32 log formula) ----
__device__ __forceinline__ int rel_bucket(int rel) {
    int rb = (rel > 0) ? 16 : 0;
    int rp = abs(rel);
    int bu;
    if (rp < 8) bu = rp;
    else if (rp < 12) bu = 8;
    else if (rp < 16) bu = 9;
    else if (rp < 23) bu = 10;
    else if (rp < 32) bu = 11;
    else if (rp < 46) bu = 12;
    else if (rp < 64) bu = 13;
    else if (rp < 91) bu = 14;
    else bu = 15;
    return rb + bu;
}

// ---------------- MFMA attention (unchanged, proven) ----------------
#define QS_STR 72
#define KS_STR 72
#define VT_STR 72
#define PL_STR 72

__global__ __launch_bounds__(256) void attn_mfma(
    const unsigned short* __restrict__ qb, const unsigned short* __restrict__ kb,
    const unsigned short* __restrict__ vb, const float* __restrict__ table,
    unsigned short* __restrict__ ao)
{
    const int n = blockIdx.x;
    const int h = blockIdx.y;
    const int b = blockIdx.z;
    const int tid = threadIdx.x;
    const int w = tid >> 6;
    const int lane = tid & 63;
    const int g = lane >> 4;
    const int li = lane & 15;

    __shared__ short Qs[128 * QS_STR];
    __shared__ short Ks[64 * KS_STR];
    __shared__ short Vt[64 * VT_STR];
    __shared__ short Pl[4][32 * PL_STR];
    __shared__ float ldsb[512];

    const unsigned short* qBase = qb + (((size_t)b * NHEAD + h) * T_LEN + (size_t)n * BLK) * HDIM;
    const unsigned short* kBase = kb + ((size_t)b * NHEAD + h) * T_LEN * HDIM;
    const unsigned short* vBase = vb + ((size_t)b * NHEAD + h) * T_LEN * HDIM;

    for (int i = tid; i < 512; i += 256) {
        ldsb[i] = table[rel_bucket(i - 255) * NHEAD + h];
    }
#pragma unroll
    for (int u = 0; u < 4; ++u) {
        int c = tid + u * 256;
        int row = c >> 3, ch = c & 7;
        *(bf16x8*)&Qs[row * QS_STR + ch * 8] =
            *(const bf16x8*)(qBase + (size_t)row * HDIM + ch * 8);
    }
    __syncthreads();

    bf16x8 aq[2][2];
#pragma unroll
    for (int mi = 0; mi < 2; ++mi)
#pragma unroll
        for (int ks = 0; ks < 2; ++ks)
            aq[mi][ks] = *(bf16x8*)&Qs[(w * 32 + mi * 16 + li) * QS_STR + ks * 32 + g * 8];

    f32x4 oacc[2][4];
    float m_run[2][4], l_run[2][4], scl[2][4];
#pragma unroll
    for (int mi = 0; mi < 2; ++mi)
#pragma unroll
        for (int r4 = 0; r4 < 4; ++r4) {
            oacc[mi][r4] = (f32x4){0.f, 0.f, 0.f, 0.f};
            m_run[mi][r4] = -1e30f;
            l_run[mi][r4] = 0.f;
        }

    for (int kt = 0; kt < 6; ++kt) {
        __syncthreads();
        const int tk0 = (n - 1) * BLK + kt * 64;
#pragma unroll
        for (int u = 0; u < 2; ++u) {
            int c = tid + u * 256;
            int row = c >> 3, ch = c & 7;
            int tok = tk0 + row;
            bf16x8 kv = {0, 0, 0, 0, 0, 0, 0, 0};
            bf16x8 vv = {0, 0, 0, 0, 0, 0, 0, 0};
            if (tok >= 0 && tok < T_LEN) {
                kv = *(const bf16x8*)(kBase + (size_t)tok * HDIM + ch * 8);
                vv = *(const bf16x8*)(vBase + (size_t)tok * HDIM + ch * 8);
            }
            *(bf16x8*)&Ks[row * KS_STR + ch * 8] = kv;
#pragma unroll
            for (int j = 0; j < 8; ++j)
                Vt[(ch * 8 + j) * VT_STR + row] = vv[j];
        }
        __syncthreads();

        f32x4 sacc[2][4];
#pragma unroll
        for (int mi = 0; mi < 2; ++mi)
#pragma unroll
            for (int ni = 0; ni < 4; ++ni)
                sacc[mi][ni] = (f32x4){0.f, 0.f, 0.f, 0.f};
#pragma unroll
        for (int ks = 0; ks < 2; ++ks) {
            bf16x8 bk[4];
#pragma unroll
            for (int ni = 0; ni < 4; ++ni)
                bk[ni] = *(bf16x8*)&Ks[(ni * 16 + li) * KS_STR + ks * 32 + g * 8];
#pragma unroll
            for (int mi = 0; mi < 2; ++mi)
#pragma unroll
                for (int ni = 0; ni < 4; ++ni)
                    sacc[mi][ni] = __builtin_amdgcn_mfma_f32_16x16x32_bf16(
                        aq[mi][ks], bk[ni], sacc[mi][ni], 0, 0, 0);
        }

#pragma unroll
        for (int mi = 0; mi < 2; ++mi) {
            const int rq = w * 32 + mi * 16 + g * 4;
#pragma unroll
            for (int reg = 0; reg < 4; ++reg) {
                const int r = rq + reg;
                float sv[4];
#pragma unroll
                for (int ni = 0; ni < 4; ++ni) {
                    int kk = kt * 64 + ni * 16 + li;
                    sv[ni] = sacc[mi][ni][reg] + ldsb[kk - r + 127];
                }
                float tm = fmaxf(fmaxf(sv[0], sv[1]), fmaxf(sv[2], sv[3]));
                tm = fmaxf(tm, __shfl_xor(tm, 1));
                tm = fmaxf(tm, __shfl_xor(tm, 2));
                tm = fmaxf(tm, __shfl_xor(tm, 4));
                tm = fmaxf(tm, __shfl_xor(tm, 8));
                float mold = m_run[mi][reg];
                float mnew = fmaxf(mold, tm);
                float sc = __expf(mold - mnew);
                float ps = 0.f;
                unsigned short pb[4];
#pragma unroll
                for (int ni = 0; ni < 4; ++ni) {
                    float pv = __expf(sv[ni] - mnew);
                    ps += pv;
                    pb[ni] = f2b(pv);
                }
                ps += __shfl_xor(ps, 1);
                ps += __shfl_xor(ps, 2);
                ps += __shfl_xor(ps, 4);
                ps += __shfl_xor(ps, 8);
                l_run[mi][reg] = l_run[mi][reg] * sc + ps;
                m_run[mi][reg] = mnew;
                scl[mi][reg] = sc;
#pragma unroll
                for (int ni = 0; ni < 4; ++ni)
                    Pl[w][(mi * 16 + g * 4 + reg) * PL_STR + ni * 16 + li] = (short)pb[ni];
            }
        }
#pragma unroll
        for (int mi = 0; mi < 2; ++mi)
#pragma unroll
            for (int dn = 0; dn < 4; ++dn)
#pragma unroll
                for (int reg = 0; reg < 4; ++reg)
                    oacc[mi][dn][reg] *= scl[mi][reg];

        __syncthreads();

#pragma unroll
        for (int ks = 0; ks < 2; ++ks) {
            bf16x8 ap[2], bv[4];
#pragma unroll
            for (int mi = 0; mi < 2; ++mi)
                ap[mi] = *(bf16x8*)&Pl[w][(mi * 16 + li) * PL_STR + ks * 32 + g * 8];
#pragma unroll
            for (int dn = 0; dn < 4; ++dn)
                bv[dn] = *(bf16x8*)&Vt[(dn * 16 + li) * VT_STR + ks * 32 + g * 8];
#pragma unroll
            for (int mi = 0; mi < 2; ++mi)
#pragma unroll
                for (int dn = 0; dn < 4; ++dn)
                    oacc[mi][dn] = __builtin_amdgcn_mfma_f32_16x16x32_bf16(
                        ap[mi], bv[dn], oacc[mi][dn], 0, 0, 0);
        }
    }

#pragma unroll
    for (int mi = 0; mi < 2; ++mi) {
#pragma unroll
        for (int reg = 0; reg < 4; ++reg) {
            float inv = 1.f / l_run[mi][reg];
            int t = n * BLK + w * 32 + mi * 16 + g * 4 + reg;
            unsigned short* orow = ao + ((size_t)b * T_LEN + t) * CDIM + h * HDIM;
#pragma unroll
            for (int dn = 0; dn < 4; ++dn)
                orow[dn * 16 + li] = f2b(oacc[mi][dn][reg] * inv);
        }
    }
}

extern "C" void kernel_launch(void* const* d_in, const int* in_sizes, int n_in,
                              void* d_out, int out_size, void* d_ws, size_t ws_size,
                              hipStream_t stream) {
    const float* hidden = (const float*)d_in[0];
    const float* Wq = (const float*)d_in[1];
    const float* Wk = (const float*)d_in[2];
    const float* Wv = (const float*)d_in[3];
    const float* Wo = (const float*)d_in[4];
    const float* table = (const float*)d_in[5];
    float* out = (float*)d_out;

    const size_t qkvElems = (size_t)BATCH * NHEAD * T_LEN * HDIM;   // 16.78M
    const size_t wElems = (size_t)CDIM * CDIM;                      // 1.05M
    const size_t needed = (4 * qkvElems + 4 * wElems) * 2;          // ~136 MiB
    if (ws_size < needed) return;

    unsigned short* qb = (unsigned short*)d_ws;
    unsigned short* kb = qb + qkvElems;
    unsigned short* vb = kb + qkvElems;
    unsigned short* xb = vb + qkvElems;     // reused as ao after proj
    unsigned short* wt = xb + qkvElems;     // [WqT|WkT|WvT|WoT], each [1024][1024]

    conv_w<<<dim3(32, 32, 4), 256, 0, stream>>>(Wq, Wk, Wv, Wo, wt);
    conv_x<<<8192, 256, 0, stream>>>(hidden, xb);
    gemm_8ph<0><<<dim3(64, 12), 512, 0, stream>>>(xb, wt, qb, kb, vb, nullptr);
    attn_mfma<<<dim3(NBLK, NHEAD, BATCH), 256, 0, stream>>>(qb, kb, vb, table, xb);
    gemm_8ph<1><<<dim3(64, 4), 512, 0, stream>>>(xb, wt + 3 * wElems,
                                                 nullptr, nullptr, nullptr, out);
}